// Round 6
// baseline (63.642 us; speedup 1.0000x reference)
//
#include <hip/hip_runtime.h>

// RFCN PSROI — algebraic restructure:
//   out[b,n,g] = B'[g] + (1/denom) * sum_{bin} Z[b,g,h,w]
//   Z = einsum('bchw,gc->bghw', features, W'),  W'[g,c] = sum_k w[g*9+k, c]
// Pipeline: (1) fold weights, (2) project features -> 25-ch partial score
// maps (8 channel-chunks, deterministic), (3) full-GPU reduce 8->1 into Z,
// (4) one block per (b,g): 2D prefix sum of Z in LDS + per-proposal 4-corner
// gather straight from LDS.

#define HW 4096      // 64*64
#define NG 25        // 21 cls + 4 reg groups
#define CIN 1024
#define B 2
#define NPROP 1000
#define NCH 8        // channel chunks
#define CK (CIN / NCH)
#define MHW (B * NG * HW)   // 204800: elements of one partial chunk / of Z

// ---------------- Kernel 1: fold weights over the K*K=9 channel groups ----
__global__ void rfcn_wfold(const float* __restrict__ w_cls,
                           const float* __restrict__ b_cls,
                           const float* __restrict__ w_reg,
                           const float* __restrict__ b_reg,
                           float* __restrict__ Wred,   // [25][1024]
                           float* __restrict__ Bred) { // [25]
    int i = blockIdx.x * 256 + threadIdx.x;
    if (i < NG * CIN) {
        int g = i >> 10, c = i & (CIN - 1);
        float s = 0.f;
        if (g < 21) {
            #pragma unroll
            for (int k = 0; k < 9; ++k) s += w_cls[(size_t)(g * 9 + k) * CIN + c];
        } else {
            int gr = g - 21;
            #pragma unroll
            for (int k = 0; k < 9; ++k) s += w_reg[(size_t)(gr * 9 + k) * CIN + c];
        }
        Wred[i] = s;
    } else if (i < NG * CIN + NG) {
        int g = i - NG * CIN;
        float s = 0.f;
        if (g < 21) {
            #pragma unroll
            for (int k = 0; k < 9; ++k) s += b_cls[g * 9 + k];
        } else {
            #pragma unroll
            for (int k = 0; k < 9; ++k) s += b_reg[(g - 21) * 9 + k];
        }
        Bred[g] = s;
    }
}

// ---------------- Kernel 2: projection  Z_partial = W' x F (channel chunk) --
// grid = (64 pixel tiles, 8 chunks, B), block = 64 (1 wave, 1 pixel/thread)
// -> 1024 blocks = 4 waves/CU; unroll 8 keeps 32 loads in flight per CU.
// part layout: [chunk][b][g][4096]
__global__ __launch_bounds__(64)
void rfcn_proj(const float* __restrict__ feats,
               const float* __restrict__ Wred,
               float* __restrict__ part) {
    const int p = blockIdx.x * 64 + threadIdx.x;    // pixel in [0,4096)
    const int chunk = blockIdx.y;
    const int b = blockIdx.z;
    const int c0 = chunk * CK;

    const float* __restrict__ f = feats + ((size_t)b * CIN + c0) * HW + p;
    const float* __restrict__ w = Wred + c0;   // uniform indices -> s_load

    float acc[NG];
    #pragma unroll
    for (int g = 0; g < NG; ++g) acc[g] = 0.f;

    #pragma unroll 8
    for (int c = 0; c < CK; ++c) {
        float fv = f[(size_t)c * HW];
        #pragma unroll
        for (int g = 0; g < NG; ++g) acc[g] += fv * w[g * CIN + c];
    }

    float* __restrict__ o = part + ((size_t)(chunk * B + b) * NG) * HW + p;
    #pragma unroll
    for (int g = 0; g < NG; ++g) o[(size_t)g * HW] = acc[g];
}

// ---------------- Kernel 3: full-GPU reduce of the 8 partial chunks --------
// grid = 800, block = 256 — reads 6.7 MB at device BW, writes Z (0.82 MB).
__global__ __launch_bounds__(256)
void rfcn_reduce(const float* __restrict__ part,
                 float* __restrict__ Z) {
    const int i = blockIdx.x * 256 + threadIdx.x;   // over 50*4096 elements
    float v[NCH];
    #pragma unroll
    for (int ch = 0; ch < NCH; ++ch) v[ch] = part[(size_t)ch * MHW + i];
    #pragma unroll
    for (int off = NCH / 2; off >= 1; off >>= 1)
        #pragma unroll
        for (int j = 0; j < off; ++j) v[j] += v[j + off];
    Z[i] = v[0];
}

// ---------------- Kernel 4: 2D prefix sum + proposal gather ----------------
// grid = 50 (m = b*25+g), block = 256 (4 waves).
// LDS 64x65: row phase conflict-free via pad; col phase stride 65 == 1
// (mod 32) -> distinct banks per lane.
__global__ __launch_bounds__(256)
void rfcn_integral_gather(const float* __restrict__ Z,
                          const int* __restrict__ props,
                          const float* __restrict__ Bred,
                          float* __restrict__ out) {
    const int m = blockIdx.x;        // b*25 + g
    const int t = threadIdx.x;
    const int lane = t & 63;
    const int wave = t >> 6;
    const int b = m / NG;
    const int g = m - b * NG;        // block-uniform
    __shared__ float tile[64 * 65];

    // phase 1: load this map's 16 KB (coalesced, independent loads)
    #pragma unroll
    for (int i = 0; i < 16; ++i) {
        const int idx = i * 256 + t;
        tile[(idx >> 6) * 65 + (idx & 63)] = Z[(size_t)m * HW + idx];
    }
    __syncthreads();

    // phase 2: row scans — wave w owns rows [w*16, w*16+16), lane = column
    #pragma unroll 2
    for (int i = 0; i < 16; ++i) {
        const int row = wave * 16 + i;
        float v = tile[row * 65 + lane];
        #pragma unroll
        for (int d = 1; d < 64; d <<= 1) {
            float u = __shfl_up(v, (unsigned)d, 64);
            if (lane >= d) v += u;
        }
        tile[row * 65 + lane] = v;
    }
    __syncthreads();

    // phase 3: column scans — wave w owns cols [w*16, w*16+16), lane = row
    #pragma unroll 2
    for (int i = 0; i < 16; ++i) {
        const int col = wave * 16 + i;
        float v = tile[lane * 65 + col];
        #pragma unroll
        for (int d = 1; d < 64; d <<= 1) {
            float u = __shfl_up(v, (unsigned)d, 64);
            if (lane >= d) v += u;
        }
        tile[lane * 65 + col] = v;
    }
    __syncthreads();

    // phase 4: per-proposal 4-corner lookups straight from LDS
    const float bias = Bred[g];
    #pragma unroll
    for (int i = 0; i < 4; ++i) {
        const int n = i * 256 + t;
        if (n < NPROP) {
            const int4 pr = ((const int4*)props)[b * NPROP + n];
            const int x1 = pr.x >> 5;            // floor(px/32), px >= 0
            const int y1 = pr.y >> 5;
            const int x2 = (pr.z + 31) >> 5;     // ceil
            const int y2 = (pr.w + 31) >> 5;
            const int wb = (x2 - x1 + 2) / 3;    // ceil((x2-x1)/3), >= 1
            const int hb = (y2 - y1 + 2) / 3;
            const int c2 = x1 + wb - 1;          // inclusive corner, <= 63
            const int r2 = y1 + hb - 1;

            float s = tile[r2 * 65 + c2];
            if (x1 > 0)           s -= tile[r2 * 65 + (x1 - 1)];
            if (y1 > 0)           s -= tile[(y1 - 1) * 65 + c2];
            if (x1 > 0 && y1 > 0) s += tile[(y1 - 1) * 65 + (x1 - 1)];
            const float v = bias + s / (float)(hb * wb);
            if (g < 21)  // block-uniform branch
                out[(size_t)(b * NPROP + n) * 21 + g] = v;
            else
                out[(size_t)(B * NPROP * 21) + (size_t)(b * NPROP + n) * 4 + (g - 21)] = v;
        }
    }
}

extern "C" void kernel_launch(void* const* d_in, const int* in_sizes, int n_in,
                              void* d_out, int out_size, void* d_ws, size_t ws_size,
                              hipStream_t stream) {
    const float* feats = (const float*)d_in[0];  // [2,1024,64,64]
    const float* w_cls = (const float*)d_in[1];  // [189,1024]
    const float* b_cls = (const float*)d_in[2];  // [189]
    const float* w_reg = (const float*)d_in[3];  // [36,1024]
    const float* b_reg = (const float*)d_in[4];  // [36]
    const int*   props = (const int*)d_in[5];    // [2,1000,4]
    float* out = (float*)d_out;
    float* ws  = (float*)d_ws;

    // workspace layout (floats): ~7.5 MB total, ws is 268 MB
    float* Wred = ws;                        // 25600
    float* Bred = ws + 25600;                // 25 (next region 128B-aligned)
    float* part = ws + 25632;                // 8 * 204800
    float* Zbuf = part + (size_t)NCH * MHW;  // 204800

    rfcn_wfold<<<(NG * CIN + NG + 255) / 256, 256, 0, stream>>>(
        w_cls, b_cls, w_reg, b_reg, Wred, Bred);
    rfcn_proj<<<dim3(HW / 64, NCH, B), 64, 0, stream>>>(feats, Wred, part);
    rfcn_reduce<<<MHW / 256, 256, 0, stream>>>(part, Zbuf);
    rfcn_integral_gather<<<B * NG, 256, 0, stream>>>(Zbuf, props, Bred, out);
}

// Round 7
// 34.355 us; speedup vs baseline: 1.8525x; 1.8525x over previous
//
#include <hip/hip_runtime.h>

// RFCN PSROI — algebraic restructure:
//   out[b,n,g] = B'[g] + (1/denom) * sum_{bin} Z[b,g,h,w]
//   Z = einsum('bchw,gc->bghw', features, W'),  W'[g,c] = sum_k w[g*9+k, c]
// Pipeline: (1) fold weights, (2) project features -> 25-ch partial score
// maps (8 channel-chunks; 4 waves/block split each chunk and LDS-reduce, so
// blocks are 256-wide -> 16 waves/CU for latency hiding), (3) full-GPU
// reduce 8->1 into Z, (4) one block per (b,g): 2D prefix sum in LDS +
// per-proposal 4-corner gather straight from LDS.

#define HW 4096      // 64*64
#define NG 25        // 21 cls + 4 reg groups
#define CIN 1024
#define B 2
#define NPROP 1000
#define NCH 8        // channel chunks written to workspace
#define CK (CIN / NCH)        // 128 channels per chunk
#define CW (CK / 4)           // 32 channels per wave
#define MHW (B * NG * HW)     // 204800: one partial chunk / Z size

// ---------------- Kernel 1: fold weights over the K*K=9 channel groups ----
__global__ void rfcn_wfold(const float* __restrict__ w_cls,
                           const float* __restrict__ b_cls,
                           const float* __restrict__ w_reg,
                           const float* __restrict__ b_reg,
                           float* __restrict__ Wred,   // [25][1024]
                           float* __restrict__ Bred) { // [25]
    int i = blockIdx.x * 256 + threadIdx.x;
    if (i < NG * CIN) {
        int g = i >> 10, c = i & (CIN - 1);
        float s = 0.f;
        if (g < 21) {
            #pragma unroll
            for (int k = 0; k < 9; ++k) s += w_cls[(size_t)(g * 9 + k) * CIN + c];
        } else {
            int gr = g - 21;
            #pragma unroll
            for (int k = 0; k < 9; ++k) s += w_reg[(size_t)(gr * 9 + k) * CIN + c];
        }
        Wred[i] = s;
    } else if (i < NG * CIN + NG) {
        int g = i - NG * CIN;
        float s = 0.f;
        if (g < 21) {
            #pragma unroll
            for (int k = 0; k < 9; ++k) s += b_cls[g * 9 + k];
        } else {
            #pragma unroll
            for (int k = 0; k < 9; ++k) s += b_reg[(g - 21) * 9 + k];
        }
        Bred[g] = s;
    }
}

// ---------------- Kernel 2: projection  Z_partial = W' x F ----------------
// grid = (64 pixel tiles, 8 chunks, B), block = 256 (4 waves).
// Wave w handles channels [chunk*128 + w*32, +32) for the block's 64 pixels;
// LDS reduce 4->1, then one coalesced partial write.
// part layout: [chunk][b][g][4096]
__global__ __launch_bounds__(256)
void rfcn_proj(const float* __restrict__ feats,
               const float* __restrict__ Wred,
               float* __restrict__ part) {
    const int t = threadIdx.x;
    const int p = t & 63;                      // pixel within tile
    // wave id via readfirstlane -> SGPR, keeps weight loads scalar (s_load)
    const int w4 = __builtin_amdgcn_readfirstlane(t >> 6);
    const int pix0 = blockIdx.x * 64;
    const int chunk = blockIdx.y;
    const int b = blockIdx.z;
    const int c0 = chunk * CK + w4 * CW;       // wave's first channel

    const float* __restrict__ f = feats + ((size_t)b * CIN + c0) * HW + pix0 + p;
    const float* __restrict__ wgt = Wred + c0; // scalar-indexed -> s_load

    float acc[NG];
    #pragma unroll
    for (int g = 0; g < NG; ++g) acc[g] = 0.f;

    // batches of 8 independent loads in flight, then FMA
    #pragma unroll
    for (int cc = 0; cc < CW; cc += 8) {
        float fv[8];
        #pragma unroll
        for (int j = 0; j < 8; ++j) fv[j] = f[(size_t)(cc + j) * HW];
        #pragma unroll
        for (int j = 0; j < 8; ++j)
            #pragma unroll
            for (int g = 0; g < NG; ++g)
                acc[g] += fv[j] * wgt[g * CIN + cc + j];
    }

    // LDS 4-wave reduction: red[w][g][p]
    __shared__ float red[4 * NG * 64];
    #pragma unroll
    for (int g = 0; g < NG; ++g) red[(w4 * NG + g) * 64 + p] = acc[g];
    __syncthreads();

    float* __restrict__ o = part + ((size_t)(chunk * B + b) * NG) * HW + pix0;
    for (int idx = t; idx < NG * 64; idx += 256) {
        const int g = idx >> 6, pp = idx & 63;
        float s = red[(0 * NG + g) * 64 + pp] + red[(1 * NG + g) * 64 + pp]
                + red[(2 * NG + g) * 64 + pp] + red[(3 * NG + g) * 64 + pp];
        o[(size_t)g * HW + pp] = s;
    }
}

// ---------------- Kernel 3: full-GPU reduce of the 8 partial chunks --------
// grid = 800, block = 256 — reads 6.7 MB at device BW, writes Z (0.82 MB).
__global__ __launch_bounds__(256)
void rfcn_reduce(const float* __restrict__ part,
                 float* __restrict__ Z) {
    const int i = blockIdx.x * 256 + threadIdx.x;   // over 50*4096 elements
    float v[NCH];
    #pragma unroll
    for (int ch = 0; ch < NCH; ++ch) v[ch] = part[(size_t)ch * MHW + i];
    #pragma unroll
    for (int off = NCH / 2; off >= 1; off >>= 1)
        #pragma unroll
        for (int j = 0; j < off; ++j) v[j] += v[j + off];
    Z[i] = v[0];
}

// ---------------- Kernel 4: 2D prefix sum + proposal gather ----------------
// grid = 50 (m = b*25+g), block = 256 (4 waves).
// LDS 64x65: row phase conflict-free via pad; col phase stride 65 == 1
// (mod 32) -> distinct banks per lane.
__global__ __launch_bounds__(256)
void rfcn_integral_gather(const float* __restrict__ Z,
                          const int* __restrict__ props,
                          const float* __restrict__ Bred,
                          float* __restrict__ out) {
    const int m = blockIdx.x;        // b*25 + g
    const int t = threadIdx.x;
    const int lane = t & 63;
    const int wave = t >> 6;
    const int b = m / NG;
    const int g = m - b * NG;        // block-uniform
    __shared__ float tile[64 * 65];

    // phase 1: load this map's 16 KB (coalesced, independent loads)
    #pragma unroll
    for (int i = 0; i < 16; ++i) {
        const int idx = i * 256 + t;
        tile[(idx >> 6) * 65 + (idx & 63)] = Z[(size_t)m * HW + idx];
    }
    __syncthreads();

    // phase 2: row scans — wave w owns rows [w*16, w*16+16), lane = column
    #pragma unroll 2
    for (int i = 0; i < 16; ++i) {
        const int row = wave * 16 + i;
        float v = tile[row * 65 + lane];
        #pragma unroll
        for (int d = 1; d < 64; d <<= 1) {
            float u = __shfl_up(v, (unsigned)d, 64);
            if (lane >= d) v += u;
        }
        tile[row * 65 + lane] = v;
    }
    __syncthreads();

    // phase 3: column scans — wave w owns cols [w*16, w*16+16), lane = row
    #pragma unroll 2
    for (int i = 0; i < 16; ++i) {
        const int col = wave * 16 + i;
        float v = tile[lane * 65 + col];
        #pragma unroll
        for (int d = 1; d < 64; d <<= 1) {
            float u = __shfl_up(v, (unsigned)d, 64);
            if (lane >= d) v += u;
        }
        tile[lane * 65 + col] = v;
    }
    __syncthreads();

    // phase 4: per-proposal 4-corner lookups straight from LDS
    const float bias = Bred[g];
    #pragma unroll
    for (int i = 0; i < 4; ++i) {
        const int n = i * 256 + t;
        if (n < NPROP) {
            const int4 pr = ((const int4*)props)[b * NPROP + n];
            const int x1 = pr.x >> 5;            // floor(px/32), px >= 0
            const int y1 = pr.y >> 5;
            const int x2 = (pr.z + 31) >> 5;     // ceil
            const int y2 = (pr.w + 31) >> 5;
            const int wb = (x2 - x1 + 2) / 3;    // ceil((x2-x1)/3), >= 1
            const int hb = (y2 - y1 + 2) / 3;
            const int c2 = x1 + wb - 1;          // inclusive corner, <= 63
            const int r2 = y1 + hb - 1;

            float s = tile[r2 * 65 + c2];
            if (x1 > 0)           s -= tile[r2 * 65 + (x1 - 1)];
            if (y1 > 0)           s -= tile[(y1 - 1) * 65 + c2];
            if (x1 > 0 && y1 > 0) s += tile[(y1 - 1) * 65 + (x1 - 1)];
            const float v = bias + s / (float)(hb * wb);
            if (g < 21)  // block-uniform branch
                out[(size_t)(b * NPROP + n) * 21 + g] = v;
            else
                out[(size_t)(B * NPROP * 21) + (size_t)(b * NPROP + n) * 4 + (g - 21)] = v;
        }
    }
}

extern "C" void kernel_launch(void* const* d_in, const int* in_sizes, int n_in,
                              void* d_out, int out_size, void* d_ws, size_t ws_size,
                              hipStream_t stream) {
    const float* feats = (const float*)d_in[0];  // [2,1024,64,64]
    const float* w_cls = (const float*)d_in[1];  // [189,1024]
    const float* b_cls = (const float*)d_in[2];  // [189]
    const float* w_reg = (const float*)d_in[3];  // [36,1024]
    const float* b_reg = (const float*)d_in[4];  // [36]
    const int*   props = (const int*)d_in[5];    // [2,1000,4]
    float* out = (float*)d_out;
    float* ws  = (float*)d_ws;

    // workspace layout (floats): ~7.5 MB total
    float* Wred = ws;                        // 25600
    float* Bred = ws + 25600;                // 25 (next region 128B-aligned)
    float* part = ws + 25632;                // 8 * 204800
    float* Zbuf = part + (size_t)NCH * MHW;  // 204800

    rfcn_wfold<<<(NG * CIN + NG + 255) / 256, 256, 0, stream>>>(
        w_cls, b_cls, w_reg, b_reg, Wred, Bred);
    rfcn_proj<<<dim3(HW / 64, NCH, B), 256, 0, stream>>>(feats, Wred, part);
    rfcn_reduce<<<MHW / 256, 256, 0, stream>>>(part, Zbuf);
    rfcn_integral_gather<<<B * NG, 256, 0, stream>>>(Zbuf, props, Bred, out);
}

// Round 8
// 34.263 us; speedup vs baseline: 1.8575x; 1.0027x over previous
//
#include <hip/hip_runtime.h>

// RFCN PSROI — algebraic restructure:
//   out[b,n,g] = B'[g] + (1/denom) * sum_{bin} Z[b,g,h,w]
//   Z = einsum('bchw,gc->bghw', features, W'),  W'[g,c] = sum_k w[g*9+k, c]
// Pipeline (3 launches):
//   (1) fold weights,
//   (2) project features -> 25-ch partial score maps (2 channel-chunks;
//       512-thread blocks, 8 waves each owning 64 channels, LDS reduce 8->1),
//   (3) per (b,g) block: sum the 2 chunks + 2D prefix sum in LDS +
//       per-proposal 4-corner gather straight from LDS.

#define HW 4096      // 64*64
#define NG 25        // 21 cls + 4 reg groups
#define CIN 1024
#define B 2
#define NPROP 1000
#define NCH 2                 // channel chunks in workspace
#define CK (CIN / NCH)        // 512 channels per chunk
#define NSL 8                 // wave slices per proj block
#define CS (CK / NSL)         // 64 channels per wave
#define MHW (B * NG * HW)     // 204800: one partial chunk

// ---------------- Kernel 1: fold weights over the K*K=9 channel groups ----
__global__ void rfcn_wfold(const float* __restrict__ w_cls,
                           const float* __restrict__ b_cls,
                           const float* __restrict__ w_reg,
                           const float* __restrict__ b_reg,
                           float* __restrict__ Wred,   // [25][1024]
                           float* __restrict__ Bred) { // [25]
    int i = blockIdx.x * 256 + threadIdx.x;
    if (i < NG * CIN) {
        int g = i >> 10, c = i & (CIN - 1);
        float s = 0.f;
        if (g < 21) {
            #pragma unroll
            for (int k = 0; k < 9; ++k) s += w_cls[(size_t)(g * 9 + k) * CIN + c];
        } else {
            int gr = g - 21;
            #pragma unroll
            for (int k = 0; k < 9; ++k) s += w_reg[(size_t)(gr * 9 + k) * CIN + c];
        }
        Wred[i] = s;
    } else if (i < NG * CIN + NG) {
        int g = i - NG * CIN;
        float s = 0.f;
        if (g < 21) {
            #pragma unroll
            for (int k = 0; k < 9; ++k) s += b_cls[g * 9 + k];
        } else {
            #pragma unroll
            for (int k = 0; k < 9; ++k) s += b_reg[(g - 21) * 9 + k];
        }
        Bred[g] = s;
    }
}

// ---------------- Kernel 2: projection  Z_partial = W' x F ----------------
// grid = (64 pixel tiles, 2 chunks, B) = 256 blocks, block = 512 (8 waves).
// Wave s handles channels [chunk*512 + s*64, +64) for the block's 64 pixels.
// 16 independent loads in flight per thread; LDS reduce 8->1; coalesced write.
// part layout: [chunk][b][g][4096]
__global__ __launch_bounds__(512)
void rfcn_proj(const float* __restrict__ feats,
               const float* __restrict__ Wred,
               float* __restrict__ part) {
    const int t = threadIdx.x;
    const int p = t & 63;                      // pixel within tile
    // wave id via readfirstlane -> SGPR, keeps weight loads scalar (s_load)
    const int sl = __builtin_amdgcn_readfirstlane(t >> 6);   // 0..7
    const int pix0 = blockIdx.x * 64;
    const int chunk = blockIdx.y;
    const int b = blockIdx.z;
    const int c0 = chunk * CK + sl * CS;       // wave's first channel

    const float* __restrict__ f = feats + ((size_t)b * CIN + c0) * HW + pix0 + p;
    const float* __restrict__ wgt = Wred + c0; // scalar-indexed -> s_load

    float acc[NG];
    #pragma unroll
    for (int g = 0; g < NG; ++g) acc[g] = 0.f;

    // batches of 16 independent loads in flight, then FMA
    #pragma unroll
    for (int cc = 0; cc < CS; cc += 16) {
        float fv[16];
        #pragma unroll
        for (int j = 0; j < 16; ++j) fv[j] = f[(size_t)(cc + j) * HW];
        #pragma unroll
        for (int j = 0; j < 16; ++j)
            #pragma unroll
            for (int g = 0; g < NG; ++g)
                acc[g] += fv[j] * wgt[g * CIN + cc + j];
    }

    // LDS 8-wave reduction: red[slice][g][p]  (8*25*64*4 = 51.2 KB)
    __shared__ float red[NSL * NG * 64];
    #pragma unroll
    for (int g = 0; g < NG; ++g) red[(sl * NG + g) * 64 + p] = acc[g];
    __syncthreads();

    float* __restrict__ o = part + ((size_t)(chunk * B + b) * NG) * HW + pix0;
    for (int idx = t; idx < NG * 64; idx += 512) {
        const int g = idx >> 6, pp = idx & 63;
        float s = 0.f;
        #pragma unroll
        for (int ss = 0; ss < NSL; ++ss) s += red[(ss * NG + g) * 64 + pp];
        o[(size_t)g * HW + pp] = s;
    }
}

// ---------------- Kernel 3: 2-chunk sum + 2D prefix sum + gather -----------
// grid = 50 (m = b*25+g), block = 256 (4 waves).
// LDS 64x65: row phase conflict-free via pad; col phase stride 65 == 1
// (mod 32) -> distinct banks per lane.
__global__ __launch_bounds__(256)
void rfcn_integral_gather(const float* __restrict__ part,
                          const int* __restrict__ props,
                          const float* __restrict__ Bred,
                          float* __restrict__ out) {
    const int m = blockIdx.x;        // b*25 + g
    const int t = threadIdx.x;
    const int lane = t & 63;
    const int wave = t >> 6;
    const int b = m / NG;
    const int g = m - b * NG;        // block-uniform
    __shared__ float tile[64 * 65];

    // phase 1: sum the 2 partial chunks (independent coalesced loads)
    #pragma unroll 4
    for (int i = 0; i < 16; ++i) {
        const int idx = i * 256 + t;
        const float v = part[(size_t)m * HW + idx]
                      + part[(size_t)(B * NG + m) * HW + idx];
        tile[(idx >> 6) * 65 + (idx & 63)] = v;
    }
    __syncthreads();

    // phase 2: row scans — wave w owns rows [w*16, w*16+16), lane = column
    #pragma unroll 2
    for (int i = 0; i < 16; ++i) {
        const int row = wave * 16 + i;
        float v = tile[row * 65 + lane];
        #pragma unroll
        for (int d = 1; d < 64; d <<= 1) {
            float u = __shfl_up(v, (unsigned)d, 64);
            if (lane >= d) v += u;
        }
        tile[row * 65 + lane] = v;
    }
    __syncthreads();

    // phase 3: column scans — wave w owns cols [w*16, w*16+16), lane = row
    #pragma unroll 2
    for (int i = 0; i < 16; ++i) {
        const int col = wave * 16 + i;
        float v = tile[lane * 65 + col];
        #pragma unroll
        for (int d = 1; d < 64; d <<= 1) {
            float u = __shfl_up(v, (unsigned)d, 64);
            if (lane >= d) v += u;
        }
        tile[lane * 65 + col] = v;
    }
    __syncthreads();

    // phase 4: per-proposal 4-corner lookups straight from LDS
    const float bias = Bred[g];
    #pragma unroll
    for (int i = 0; i < 4; ++i) {
        const int n = i * 256 + t;
        if (n < NPROP) {
            const int4 pr = ((const int4*)props)[b * NPROP + n];
            const int x1 = pr.x >> 5;            // floor(px/32), px >= 0
            const int y1 = pr.y >> 5;
            const int x2 = (pr.z + 31) >> 5;     // ceil
            const int y2 = (pr.w + 31) >> 5;
            const int wb = (x2 - x1 + 2) / 3;    // ceil((x2-x1)/3), >= 1
            const int hb = (y2 - y1 + 2) / 3;
            const int c2 = x1 + wb - 1;          // inclusive corner, <= 63
            const int r2 = y1 + hb - 1;

            float s = tile[r2 * 65 + c2];
            if (x1 > 0)           s -= tile[r2 * 65 + (x1 - 1)];
            if (y1 > 0)           s -= tile[(y1 - 1) * 65 + c2];
            if (x1 > 0 && y1 > 0) s += tile[(y1 - 1) * 65 + (x1 - 1)];
            const float v = bias + s / (float)(hb * wb);
            if (g < 21)  // block-uniform branch
                out[(size_t)(b * NPROP + n) * 21 + g] = v;
            else
                out[(size_t)(B * NPROP * 21) + (size_t)(b * NPROP + n) * 4 + (g - 21)] = v;
        }
    }
}

extern "C" void kernel_launch(void* const* d_in, const int* in_sizes, int n_in,
                              void* d_out, int out_size, void* d_ws, size_t ws_size,
                              hipStream_t stream) {
    const float* feats = (const float*)d_in[0];  // [2,1024,64,64]
    const float* w_cls = (const float*)d_in[1];  // [189,1024]
    const float* b_cls = (const float*)d_in[2];  // [189]
    const float* w_reg = (const float*)d_in[3];  // [36,1024]
    const float* b_reg = (const float*)d_in[4];  // [36]
    const int*   props = (const int*)d_in[5];    // [2,1000,4]
    float* out = (float*)d_out;
    float* ws  = (float*)d_ws;

    // workspace layout (floats): ~1.8 MB total
    float* Wred = ws;                        // 25600
    float* Bred = ws + 25600;                // 25 (next region 128B-aligned)
    float* part = ws + 25632;                // 2 * 204800

    rfcn_wfold<<<(NG * CIN + NG + 255) / 256, 256, 0, stream>>>(
        w_cls, b_cls, w_reg, b_reg, Wred, Bred);
    rfcn_proj<<<dim3(HW / 64, NCH, B), 512, 0, stream>>>(feats, Wred, part);
    rfcn_integral_gather<<<B * NG, 256, 0, stream>>>(part, props, Bred, out);
}

// Round 9
// 27.798 us; speedup vs baseline: 2.2895x; 1.2326x over previous
//
#include <hip/hip_runtime.h>

// RFCN PSROI — algebraic restructure:
//   out[b,n,g] = B'[g] + (1/denom) * sum_{bin} Z[b,g,h,w]
//   Z = einsum('bchw,gc->bghw', features, W'),  W'[g,c] = sum_k w[g*9+k, c]
// Pipeline (3 launches):
//   (1) fold weights,
//   (2) project features -> 25-ch partial score maps (2 channel-chunks;
//       1024-thread blocks, 16 waves each owning 32 channels, LDS 16->1),
//   (3) per (b,g) block (1024 thr): sum 2 chunks + 2D prefix sum in LDS +
//       per-proposal 4-corner gather straight from LDS.

#define HW 4096      // 64*64
#define NG 25        // 21 cls + 4 reg groups
#define CIN 1024
#define B 2
#define NPROP 1000
#define NCH 2                 // channel chunks in workspace
#define CK (CIN / NCH)        // 512 channels per chunk
#define NSL 16                // wave slices per proj block
#define CS (CK / NSL)         // 32 channels per wave
#define MHW (B * NG * HW)     // 204800: one partial chunk

// ---------------- Kernel 1: fold weights over the K*K=9 channel groups ----
__global__ void rfcn_wfold(const float* __restrict__ w_cls,
                           const float* __restrict__ b_cls,
                           const float* __restrict__ w_reg,
                           const float* __restrict__ b_reg,
                           float* __restrict__ Wred,   // [25][1024]
                           float* __restrict__ Bred) { // [25]
    int i = blockIdx.x * 256 + threadIdx.x;
    if (i < NG * CIN) {
        int g = i >> 10, c = i & (CIN - 1);
        float s = 0.f;
        if (g < 21) {
            #pragma unroll
            for (int k = 0; k < 9; ++k) s += w_cls[(size_t)(g * 9 + k) * CIN + c];
        } else {
            int gr = g - 21;
            #pragma unroll
            for (int k = 0; k < 9; ++k) s += w_reg[(size_t)(gr * 9 + k) * CIN + c];
        }
        Wred[i] = s;
    } else if (i < NG * CIN + NG) {
        int g = i - NG * CIN;
        float s = 0.f;
        if (g < 21) {
            #pragma unroll
            for (int k = 0; k < 9; ++k) s += b_cls[g * 9 + k];
        } else {
            #pragma unroll
            for (int k = 0; k < 9; ++k) s += b_reg[(g - 21) * 9 + k];
        }
        Bred[g] = s;
    }
}

// ---------------- Kernel 2: projection  Z_partial = W' x F ----------------
// grid = (64 pixel tiles, 2 chunks, B) = 256 blocks, block = 1024 (16 waves).
// Wave s handles channels [chunk*512 + s*32, +32) for the block's 64 pixels.
// 16 independent loads in flight per thread -> 64 KB/CU in flight; LDS 16->1.
// part layout: [chunk][b][g][4096]
__global__ __launch_bounds__(1024)
void rfcn_proj(const float* __restrict__ feats,
               const float* __restrict__ Wred,
               float* __restrict__ part) {
    const int t = threadIdx.x;
    const int p = t & 63;                      // pixel within tile
    // wave id via readfirstlane -> SGPR, keeps weight loads scalar (s_load)
    const int sl = __builtin_amdgcn_readfirstlane(t >> 6);   // 0..15
    const int pix0 = blockIdx.x * 64;
    const int chunk = blockIdx.y;
    const int b = blockIdx.z;
    const int c0 = chunk * CK + sl * CS;       // wave's first channel

    const float* __restrict__ f = feats + ((size_t)b * CIN + c0) * HW + pix0 + p;
    const float* __restrict__ wgt = Wred + c0; // scalar-indexed -> s_load

    float acc[NG];
    #pragma unroll
    for (int g = 0; g < NG; ++g) acc[g] = 0.f;

    // batches of 16 independent loads in flight, then FMA
    #pragma unroll
    for (int cc = 0; cc < CS; cc += 16) {
        float fv[16];
        #pragma unroll
        for (int j = 0; j < 16; ++j) fv[j] = f[(size_t)(cc + j) * HW];
        #pragma unroll
        for (int j = 0; j < 16; ++j)
            #pragma unroll
            for (int g = 0; g < NG; ++g)
                acc[g] += fv[j] * wgt[g * CIN + cc + j];
    }

    // LDS 16-wave reduction: red[slice][g][p]  (16*25*64*4 = 100 KB)
    __shared__ float red[NSL * NG * 64];
    #pragma unroll
    for (int g = 0; g < NG; ++g) red[(sl * NG + g) * 64 + p] = acc[g];
    __syncthreads();

    float* __restrict__ o = part + ((size_t)(chunk * B + b) * NG) * HW + pix0;
    for (int idx = t; idx < NG * 64; idx += 1024) {
        const int g = idx >> 6, pp = idx & 63;
        float s = 0.f;
        #pragma unroll
        for (int ss = 0; ss < NSL; ++ss) s += red[(ss * NG + g) * 64 + pp];
        o[(size_t)g * HW + pp] = s;
    }
}

// ---------------- Kernel 3: 2-chunk sum + 2D prefix sum + gather -----------
// grid = 50 (m = b*25+g), block = 1024 (16 waves) — each wave scans only
// 4 rows then 4 cols (independent 6-deep shfl chains, 4 waves/SIMD).
// LDS 64x65: row phase conflict-free via pad; col phase stride 65 == 1
// (mod 32) -> distinct banks per lane.
__global__ __launch_bounds__(1024)
void rfcn_integral_gather(const float* __restrict__ part,
                          const int* __restrict__ props,
                          const float* __restrict__ Bred,
                          float* __restrict__ out) {
    const int m = blockIdx.x;        // b*25 + g
    const int t = threadIdx.x;
    const int lane = t & 63;
    const int wave = t >> 6;         // 0..15
    const int b = m / NG;
    const int g = m - b * NG;        // block-uniform
    __shared__ float tile[64 * 65];

    // phase 1: sum the 2 partial chunks (8 independent coalesced loads)
    #pragma unroll
    for (int i = 0; i < 4; ++i) {
        const int idx = i * 1024 + t;
        const float v = part[(size_t)m * HW + idx]
                      + part[(size_t)(B * NG + m) * HW + idx];
        tile[(idx >> 6) * 65 + (idx & 63)] = v;
    }
    __syncthreads();

    // phase 2: row scans — wave w owns rows [w*4, w*4+4), lane = column
    #pragma unroll
    for (int i = 0; i < 4; ++i) {
        const int row = wave * 4 + i;
        float v = tile[row * 65 + lane];
        #pragma unroll
        for (int d = 1; d < 64; d <<= 1) {
            float u = __shfl_up(v, (unsigned)d, 64);
            if (lane >= d) v += u;
        }
        tile[row * 65 + lane] = v;
    }
    __syncthreads();

    // phase 3: column scans — wave w owns cols [w*4, w*4+4), lane = row
    #pragma unroll
    for (int i = 0; i < 4; ++i) {
        const int col = wave * 4 + i;
        float v = tile[lane * 65 + col];
        #pragma unroll
        for (int d = 1; d < 64; d <<= 1) {
            float u = __shfl_up(v, (unsigned)d, 64);
            if (lane >= d) v += u;
        }
        tile[lane * 65 + col] = v;
    }
    __syncthreads();

    // phase 4: per-proposal 4-corner lookups straight from LDS
    const float bias = Bred[g];
    const int n = t;
    if (n < NPROP) {
        const int4 pr = ((const int4*)props)[b * NPROP + n];
        const int x1 = pr.x >> 5;            // floor(px/32), px >= 0
        const int y1 = pr.y >> 5;
        const int x2 = (pr.z + 31) >> 5;     // ceil
        const int y2 = (pr.w + 31) >> 5;
        const int wb = (x2 - x1 + 2) / 3;    // ceil((x2-x1)/3), >= 1
        const int hb = (y2 - y1 + 2) / 3;
        const int c2 = x1 + wb - 1;          // inclusive corner, <= 63
        const int r2 = y1 + hb - 1;

        float s = tile[r2 * 65 + c2];
        if (x1 > 0)           s -= tile[r2 * 65 + (x1 - 1)];
        if (y1 > 0)           s -= tile[(y1 - 1) * 65 + c2];
        if (x1 > 0 && y1 > 0) s += tile[(y1 - 1) * 65 + (x1 - 1)];
        const float v = bias + s / (float)(hb * wb);
        if (g < 21)  // block-uniform branch
            out[(size_t)(b * NPROP + n) * 21 + g] = v;
        else
            out[(size_t)(B * NPROP * 21) + (size_t)(b * NPROP + n) * 4 + (g - 21)] = v;
    }
}

extern "C" void kernel_launch(void* const* d_in, const int* in_sizes, int n_in,
                              void* d_out, int out_size, void* d_ws, size_t ws_size,
                              hipStream_t stream) {
    const float* feats = (const float*)d_in[0];  // [2,1024,64,64]
    const float* w_cls = (const float*)d_in[1];  // [189,1024]
    const float* b_cls = (const float*)d_in[2];  // [189]
    const float* w_reg = (const float*)d_in[3];  // [36,1024]
    const float* b_reg = (const float*)d_in[4];  // [36]
    const int*   props = (const int*)d_in[5];    // [2,1000,4]
    float* out = (float*)d_out;
    float* ws  = (float*)d_ws;

    // workspace layout (floats): ~1.8 MB total
    float* Wred = ws;                        // 25600
    float* Bred = ws + 25600;                // 25 (next region 128B-aligned)
    float* part = ws + 25632;                // 2 * 204800

    rfcn_wfold<<<(NG * CIN + NG + 255) / 256, 256, 0, stream>>>(
        w_cls, b_cls, w_reg, b_reg, Wred, Bred);
    rfcn_proj<<<dim3(HW / 64, NCH, B), 1024, 0, stream>>>(feats, Wred, part);
    rfcn_integral_gather<<<B * NG, 1024, 0, stream>>>(part, props, Bred, out);
}